// Round 1
// baseline (160.047 us; speedup 1.0000x reference)
//
#include <hip/hip_runtime.h>
#include <math.h>

#define T_STEPS 32
#define B_EV    256
#define N_HITS  500000
#define N_PFO   4096

// Workspace layout (bytes):
//   [0,64)      double sums[8]: 0=dir 1=mag 2=pid 3=chg 4=stop 5=assign
//   [64,80)     int icnt[4]:    0=valid_pfo_count 1=assign_valid_count
//   [80,1104)   int ppe[256]
//   [1104,2128) int first_idx[256]

__device__ __forceinline__ float softplusf(float x) {
    // log(1+exp(x)), numerically stable
    return fmaxf(x, 0.f) + __logf(1.f + __expf(-fabsf(x)));
}

__device__ __forceinline__ float waveReduceF(float v) {
#pragma unroll
    for (int o = 32; o > 0; o >>= 1) v += __shfl_down(v, o, 64);
    return v;
}
__device__ __forceinline__ int waveReduceI(int v) {
#pragma unroll
    for (int o = 32; o > 0; o >>= 1) v += __shfl_down(v, o, 64);
    return v;
}

__device__ __forceinline__ int lowerBound(const int* __restrict__ a, int n, int key) {
    int lo = 0, hi = n;
    while (lo < hi) {
        int m = (lo + hi) >> 1;
        if (a[m] < key) lo = m + 1; else hi = m;
    }
    return lo;
}

// --- Kernel 1: ppe / first_idx via binary search over sorted gt_batch; zero accumulators.
__global__ void k_setup(const int* __restrict__ gt_batch,
                        double* __restrict__ sums, int* __restrict__ icnt,
                        int* __restrict__ ppe, int* __restrict__ first_idx) {
    int b = threadIdx.x;  // one block of 256
    if (b < 8) sums[b] = 0.0;
    if (b >= 8 && b < 12) icnt[b - 8] = 0;
    int lb = lowerBound(gt_batch, N_PFO, b);
    int ub = lowerBound(gt_batch, N_PFO, b + 1);
    ppe[b] = ub - lb;
    first_idx[b] = lb;
}

// --- Kernel 2: per-pfo losses (dir/mag/pid/charge) + stop BCE, fused.
__global__ void k_small(const float* __restrict__ pfo_mom, const float* __restrict__ pfo_pmod,
                        const float* __restrict__ pfo_pid, const float* __restrict__ pfo_chg,
                        const float* __restrict__ stop_logits,
                        const float* __restrict__ gt_mom, const float* __restrict__ gt_pmod,
                        const float* __restrict__ gt_pid, const float* __restrict__ gt_chg,
                        const int* __restrict__ gt_batch,
                        const int* __restrict__ ppe, const int* __restrict__ first_idx,
                        double* __restrict__ sums, int* __restrict__ icnt) {
    int tid = blockIdx.x * blockDim.x + threadIdx.x;
    float s_stop = 0.f, s_dir = 0.f, s_mag = 0.f, s_pid = 0.f, s_chg = 0.f;
    int cnt = 0;

    if (tid < T_STEPS * B_EV) {  // stop loss over (T,B)
        int t = tid >> 8, b = tid & 255;
        float x = stop_logits[tid];
        float z = (t >= ppe[b]) ? 1.f : 0.f;
        s_stop = softplusf(x) - x * z;
    }

    if (tid < N_PFO) {
        int i = tid;
        int b = gt_batch[i];
        int step = i - first_idx[b];
        if (step < T_STEPS) {
            cnt = 1;
            int base = step * B_EV + b;
            // direction: 1 - cosine similarity (normalize with eps=1e-8)
            float p0 = pfo_mom[base * 3 + 0], p1 = pfo_mom[base * 3 + 1], p2 = pfo_mom[base * 3 + 2];
            float g0 = gt_mom[i * 3 + 0],    g1 = gt_mom[i * 3 + 1],    g2 = gt_mom[i * 3 + 2];
            float pn = fmaxf(sqrtf(p0 * p0 + p1 * p1 + p2 * p2), 1e-8f);
            float gn = fmaxf(sqrtf(g0 * g0 + g1 * g1 + g2 * g2), 1e-8f);
            float cs = (p0 * g0 + p1 * g1 + p2 * g2) / (pn * gn);
            s_dir = 1.f - cs;
            // magnitude MSE
            float dm = pfo_pmod[base] - gt_pmod[i];
            s_mag = dm * dm;
            // PID: NLL vs argmax(gt_pid) (first-max tie-break like jnp.argmax)
            int cls = 0;
            float best = gt_pid[i * 5];
#pragma unroll
            for (int c = 1; c < 5; c++) {
                float v = gt_pid[i * 5 + c];
                if (v > best) { best = v; cls = c; }
            }
            float l[5];
#pragma unroll
            for (int c = 0; c < 5; c++) l[c] = pfo_pid[base * 5 + c];
            float m = l[0];
#pragma unroll
            for (int c = 1; c < 5; c++) m = fmaxf(m, l[c]);
            float se = 0.f;
#pragma unroll
            for (int c = 0; c < 5; c++) se += __expf(l[c] - m);
            float lse = __logf(se) + m;
            s_pid = lse - l[cls];
            // charge MSE
            float dc = pfo_chg[base] - gt_chg[i];
            s_chg = dc * dc;
        }
    }

    s_dir = waveReduceF(s_dir);
    s_mag = waveReduceF(s_mag);
    s_pid = waveReduceF(s_pid);
    s_chg = waveReduceF(s_chg);
    s_stop = waveReduceF(s_stop);
    cnt = waveReduceI(cnt);
    if ((threadIdx.x & 63) == 0) {
        atomicAdd(&sums[0], (double)s_dir);
        atomicAdd(&sums[1], (double)s_mag);
        atomicAdd(&sums[2], (double)s_pid);
        atomicAdd(&sums[3], (double)s_chg);
        atomicAdd(&sums[4], (double)s_stop);
        atomicAdd(&icnt[0], cnt);
    }
}

// --- Kernel 3: assignment BCE over (T,N), reading only valid rows (t < min(ppe,T)).
__global__ void __launch_bounds__(256) k_assign(const float* __restrict__ A,
                                                const int* __restrict__ hit_to_pfo,
                                                const int* __restrict__ hit_batch,
                                                const int* __restrict__ ppe,
                                                double* __restrict__ sums, int* __restrict__ icnt) {
    int q = blockIdx.x * blockDim.x + threadIdx.x;  // quad-column index
    float s = 0.f;
    int cnt = 0;
    if (q < N_HITS / 4) {
        int n0 = q * 4;
        int4 hb = *(const int4*)(hit_batch + n0);
        int4 hp = *(const int4*)(hit_to_pfo + n0);
        int v0 = min(ppe[hb.x], T_STEPS);
        int v1 = min(ppe[hb.y], T_STEPS);
        int v2 = min(ppe[hb.z], T_STEPS);
        int v3 = min(ppe[hb.w], T_STEPS);
        cnt = v0 + v1 + v2 + v3;
        int vmax = max(max(v0, v1), max(v2, v3));
        const float* col = A + n0;
#pragma unroll 4
        for (int t = 0; t < vmax; t++) {
            float4 x = *(const float4*)(col + (size_t)t * N_HITS);
            if (t < v0) s += softplusf(x.x) - ((t == hp.x) ? x.x : 0.f);
            if (t < v1) s += softplusf(x.y) - ((t == hp.y) ? x.y : 0.f);
            if (t < v2) s += softplusf(x.z) - ((t == hp.z) ? x.z : 0.f);
            if (t < v3) s += softplusf(x.w) - ((t == hp.w) ? x.w : 0.f);
        }
    }
    s = waveReduceF(s);
    cnt = waveReduceI(cnt);
    if ((threadIdx.x & 63) == 0) {
        atomicAdd(&sums[5], (double)s);
        atomicAdd(&icnt[1], cnt);
    }
}

// --- Kernel 4: finalize the 7 outputs.
__global__ void k_final(const double* __restrict__ sums, const int* __restrict__ icnt,
                        float* __restrict__ out) {
    if (threadIdx.x == 0 && blockIdx.x == 0) {
        double vc = (double)(icnt[0] > 1 ? icnt[0] : 1);
        double ac = (double)(icnt[1] > 1 ? icnt[1] : 1);
        double dir = sums[0] / vc;
        double mag = sums[1] / vc;
        double pid = sums[2] / vc;
        double chg = sums[3] / vc;
        double stp = sums[4] / (double)(T_STEPS * B_EV);
        double asn = sums[5] / ac;
        double total = 1.0 * dir + 1.0 * mag + 1.0 * pid + 0.5 * chg + 1.0 * asn + 0.5 * stp;
        out[0] = (float)total;
        out[1] = (float)dir;
        out[2] = (float)mag;
        out[3] = (float)pid;
        out[4] = (float)chg;
        out[5] = (float)asn;
        out[6] = (float)stp;
    }
}

extern "C" void kernel_launch(void* const* d_in, const int* in_sizes, int n_in,
                              void* d_out, int out_size, void* d_ws, size_t ws_size,
                              hipStream_t stream) {
    (void)in_sizes; (void)n_in; (void)out_size; (void)ws_size;
    const float* pfo_mom   = (const float*)d_in[0];
    const float* pfo_pmod  = (const float*)d_in[1];
    const float* pfo_pid   = (const float*)d_in[2];
    const float* pfo_chg   = (const float*)d_in[3];
    const float* assign_lg = (const float*)d_in[4];
    const float* stop_lg   = (const float*)d_in[5];
    const float* gt_mom    = (const float*)d_in[6];
    const float* gt_pmod   = (const float*)d_in[7];
    const float* gt_pid    = (const float*)d_in[8];
    const float* gt_chg    = (const float*)d_in[9];
    const int*   gt_batch  = (const int*)d_in[10];
    const int*   hit_to_pfo= (const int*)d_in[11];
    const int*   hit_batch = (const int*)d_in[12];
    float* out = (float*)d_out;

    char* ws = (char*)d_ws;
    double* sums    = (double*)(ws + 0);
    int*    icnt    = (int*)(ws + 64);
    int*    ppe     = (int*)(ws + 80);
    int*    firstIx = (int*)(ws + 1104);

    k_setup<<<1, 256, 0, stream>>>(gt_batch, sums, icnt, ppe, firstIx);
    k_small<<<(T_STEPS * B_EV) / 256, 256, 0, stream>>>(
        pfo_mom, pfo_pmod, pfo_pid, pfo_chg, stop_lg,
        gt_mom, gt_pmod, gt_pid, gt_chg, gt_batch, ppe, firstIx, sums, icnt);
    int nq = N_HITS / 4;
    k_assign<<<(nq + 255) / 256, 256, 0, stream>>>(assign_lg, hit_to_pfo, hit_batch, ppe, sums, icnt);
    k_final<<<1, 64, 0, stream>>>(sums, icnt, out);
}